// Round 2
// baseline (1236.261 us; speedup 1.0000x reference)
//
#include <hip/hip_runtime.h>

#define N_VAR   100000
#define N_CSTR  50000
#define NEDGE   1000000
#define DIM     64

// ---------------------------------------------------------------------------
// Workspace layout (4-byte units):
//   0:        deg_node   100000  (int)
//   100000:   deg_cstr    50000  (int)
//   150000:   off_node   100001  (int)
//   250001:   off_cstr    50001  (int)
//   300002:   cur_node   100000  (int)
//   400002:   cur_cstr    50000  (int)
//   450002:   stats         256  (float: node sum/sq, cstr sum/sq)
//   450258:   ab            256  (float: a_n,b_n,a_c,b_c)
//   450514:   entries_node 2000000 (int2 per edge: {src_idx, w_bits})
//   2450514:  entries_cstr 2000000
// Total ~17.8 MB.
// ---------------------------------------------------------------------------
#define OFF_DEG_N   0
#define OFF_DEG_C   100000
#define OFF_OFF_N   150000
#define OFF_OFF_C   250001
#define OFF_CUR_N   300002
#define OFF_CUR_C   400002
#define OFF_STATS   450002
#define OFF_AB      450258
#define OFF_ENT_N   450514
#define OFF_ENT_C   2450514
#define WS_ZERO_N   450514   // zero everything below entries

// ---------------------------------------------------------------------------
// BN column stats: partial sum/sumsq per column -> atomics into stats.
// ---------------------------------------------------------------------------
__global__ __launch_bounds__(256) void bn_stats_k(const float* __restrict__ x, int n,
                                                  float* __restrict__ stats) {
  int c = threadIdx.x & 63;
  int rg = threadIdx.x >> 6;
  float s = 0.f, q = 0.f;
  for (int r = blockIdx.x * 4 + rg; r < n; r += gridDim.x * 4) {
    float v = x[r * DIM + c];
    s += v;
    q += v * v;
  }
  __shared__ float sb[256], qb[256];
  sb[threadIdx.x] = s;
  qb[threadIdx.x] = q;
  __syncthreads();
  if (rg == 0) {
    s = sb[c] + sb[c + 64] + sb[c + 128] + sb[c + 192];
    q = qb[c] + qb[c + 64] + qb[c + 128] + qb[c + 192];
    atomicAdd(&stats[c], s);
    atomicAdd(&stats[64 + c], q);
  }
}

__global__ void bn_finalize_k(const float* __restrict__ stats,
                              const float* __restrict__ gn, const float* __restrict__ bn,
                              const float* __restrict__ gc, const float* __restrict__ bc,
                              float* __restrict__ ab) {
  int t = threadIdx.x;  // 0..127
  int c = t & 63;
  bool isC = t >= 64;
  const float* st = stats + (isC ? 128 : 0);
  float n = isC ? (float)N_CSTR : (float)N_VAR;
  float mean = st[c] / n;
  float var = st[64 + c] / n - mean * mean;
  float g = isC ? gc[c] : gn[c];
  float be = isC ? bc[c] : bn[c];
  float a = g * rsqrtf(var + 1e-5f);
  float b = be - mean * a;
  float* o = ab + (isC ? 128 : 0);
  o[c] = a;
  o[64 + c] = b;
}

// ---------------------------------------------------------------------------
// Degree histogram: int atomics (cheap vs 128M float atomics).
// ---------------------------------------------------------------------------
__global__ __launch_bounds__(256) void hist_k(const int* __restrict__ esrc,
                                              const int* __restrict__ edst,
                                              int* __restrict__ deg_node,
                                              int* __restrict__ deg_cstr) {
  int e = blockIdx.x * blockDim.x + threadIdx.x;
  if (e < NEDGE) {
    atomicAdd(&deg_node[edst[e]], 1);
    atomicAdd(&deg_cstr[esrc[e]], 1);
  }
}

// ---------------------------------------------------------------------------
// Exclusive scan, one workgroup per array (block 0: node, block 1: cstr).
// Writes off[] and a working copy cur[] for the fill pass; off[n] = NEDGE.
// ---------------------------------------------------------------------------
__global__ __launch_bounds__(1024) void scan_k(int* __restrict__ ws) {
  const int* deg = (blockIdx.x == 0) ? ws + OFF_DEG_N : ws + OFF_DEG_C;
  int* off = (blockIdx.x == 0) ? ws + OFF_OFF_N : ws + OFF_OFF_C;
  int* cur = (blockIdx.x == 0) ? ws + OFF_CUR_N : ws + OFF_CUR_C;
  int n = (blockIdx.x == 0) ? N_VAR : N_CSTR;
  int t = threadIdx.x;
  int chunk = (n + 1023) / 1024;
  int lo = t * chunk, hi = min(n, lo + chunk);
  int s = 0;
  for (int i = lo; i < hi; ++i) s += deg[i];
  __shared__ int sb[1024];
  sb[t] = s;
  __syncthreads();
  // Hillis-Steele inclusive scan
  for (int d = 1; d < 1024; d <<= 1) {
    int v = (t >= d) ? sb[t - d] : 0;
    __syncthreads();
    sb[t] += v;
    __syncthreads();
  }
  int run = sb[t] - s;  // exclusive prefix of this thread's chunk
  for (int i = lo; i < hi; ++i) {
    off[i] = run;
    cur[i] = run;
    run += deg[i];
  }
  if (t == 0) off[n] = NEDGE;
}

// ---------------------------------------------------------------------------
// Fill CSR buckets: entries_node[dst bucket] = {src, w}; entries_cstr[src] = {dst, w}.
// ---------------------------------------------------------------------------
__global__ __launch_bounds__(256) void fill_k(const int* __restrict__ esrc,
                                              const int* __restrict__ edst,
                                              const float* __restrict__ eattr,
                                              int* __restrict__ cur_node,
                                              int* __restrict__ cur_cstr,
                                              int2* __restrict__ ent_node,
                                              int2* __restrict__ ent_cstr) {
  int e = blockIdx.x * blockDim.x + threadIdx.x;
  if (e < NEDGE) {
    int s = esrc[e];
    int d = edst[e];
    int wb = __float_as_int(eattr[e]);
    int p0 = atomicAdd(&cur_node[d], 1);
    ent_node[p0] = make_int2(s, wb);
    int p1 = atomicAdd(&cur_cstr[s], 1);
    ent_cstr[p1] = make_int2(d, wb);
  }
}

// ---------------------------------------------------------------------------
// Fused gather + GEMM + epilogue. One wave per destination row (grid-stride):
//   agg[c]  = (1/max(deg,1)) * sum_e (src[nbr_e][c]*a_s + b_s) * w_e
//   xv[c]   = raw[r][c]*a_d + b_d
//   out[r][c] = relu( agg . w_rel[c][:] + b_rel[c] + xv . w_root[c][:] + xv[c] )
// Weights live in registers (lane c holds w_rel[c][:], w_root[c][:]); the agg/xv
// rows round-trip a per-wave LDS slice and are read back as broadcast float4
// (conflict-free). No __syncthreads: each wave owns its LDS rows.
// ---------------------------------------------------------------------------
__global__ __launch_bounds__(256) void gather_out_k(
    const float* __restrict__ raw,       // dst-side raw features [n, 64]
    const float* __restrict__ srcf,      // src-side raw features
    const int2* __restrict__ ent,        // CSR entries {src_idx, w_bits}
    const int* __restrict__ off,         // CSR offsets [n+1]
    const float* __restrict__ ab_dst,    // a,b for dst-side BN
    const float* __restrict__ ab_src,    // a,b for src-side BN
    const float* __restrict__ w_rel, const float* __restrict__ b_rel,
    const float* __restrict__ w_root,
    float* __restrict__ out, int n) {
  __shared__ float rowA[4][DIM];
  __shared__ float rowX[4][DIM];
  int lane = threadIdx.x & 63;
  int wv = threadIdx.x >> 6;
  float a_d = ab_dst[lane], b_d = ab_dst[64 + lane];
  float a_s = ab_src[lane], b_s = ab_src[64 + lane];
  float brel = b_rel[lane];
  float4 wr[16], wo[16];
#pragma unroll
  for (int i = 0; i < 16; ++i) {
    wr[i] = reinterpret_cast<const float4*>(w_rel + lane * DIM)[i];
    wo[i] = reinterpret_cast<const float4*>(w_root + lane * DIM)[i];
  }
  int wave = (blockIdx.x * blockDim.x + threadIdx.x) >> 6;
  int nw = (gridDim.x * blockDim.x) >> 6;
  for (int r = wave; r < n; r += nw) {
    int beg = off[r], end = off[r + 1];
    float acc = 0.f;
    int e = beg;
    if (e < end) {
      int2 c0 = ent[e];
      while (true) {
        float v = srcf[(long)c0.x * DIM + lane];
        bool more = (e + 1 < end);
        int2 c1;
        if (more) c1 = ent[e + 1];  // prefetch next entry before consuming v
        acc += (v * a_s + b_s) * __int_as_float(c0.y);
        if (!more) break;
        c0 = c1;
        ++e;
      }
    }
    float deg = (float)(end - beg);
    acc = acc / fmaxf(deg, 1.f);
    float xv = raw[(long)r * DIM + lane] * a_d + b_d;
    rowA[wv][lane] = acc;
    rowX[wv][lane] = xv;
    const float4* RA = reinterpret_cast<const float4*>(rowA[wv]);
    const float4* RX = reinterpret_cast<const float4*>(rowX[wv]);
    float acc0 = 0.f, acc1 = 0.f, acc2 = 0.f, acc3 = 0.f;
#pragma unroll
    for (int i = 0; i < 16; ++i) {
      float4 ra = RA[i];
      float4 rx = RX[i];
      acc0 += ra.x * wr[i].x + ra.y * wr[i].y;
      acc1 += ra.z * wr[i].z + ra.w * wr[i].w;
      acc2 += rx.x * wo[i].x + rx.y * wo[i].y;
      acc3 += rx.z * wo[i].z + rx.w * wo[i].w;
    }
    out[(long)r * DIM + lane] = fmaxf((acc0 + acc1) + brel + (acc2 + acc3) + xv, 0.f);
  }
}

extern "C" void kernel_launch(void* const* d_in, const int* in_sizes, int n_in,
                              void* d_out, int out_size, void* d_ws, size_t ws_size,
                              hipStream_t stream) {
  const float* vf = (const float*)d_in[0];
  const float* cf = (const float*)d_in[1];
  const int* es = (const int*)d_in[2];
  const int* ed = (const int*)d_in[3];
  const float* ea = (const float*)d_in[4];
  const float* gn = (const float*)d_in[5];
  const float* bn = (const float*)d_in[6];
  const float* gc = (const float*)d_in[7];
  const float* bc = (const float*)d_in[8];
  const float* n_rel_w = (const float*)d_in[9];
  const float* n_rel_b = (const float*)d_in[10];
  const float* n_root_w = (const float*)d_in[11];
  const float* c_rel_w = (const float*)d_in[12];
  const float* c_rel_b = (const float*)d_in[13];
  const float* c_root_w = (const float*)d_in[14];
  float* out = (float*)d_out;
  int* wsi = (int*)d_ws;
  float* wsf = (float*)d_ws;

  int* deg_node = wsi + OFF_DEG_N;
  int* deg_cstr = wsi + OFF_DEG_C;
  int* off_node = wsi + OFF_OFF_N;
  int* off_cstr = wsi + OFF_OFF_C;
  int* cur_node = wsi + OFF_CUR_N;
  int* cur_cstr = wsi + OFF_CUR_C;
  float* stats = wsf + OFF_STATS;
  float* ab = wsf + OFF_AB;
  int2* ent_node = (int2*)(wsi + OFF_ENT_N);
  int2* ent_cstr = (int2*)(wsi + OFF_ENT_C);

  // Zero deg/off/cur/stats (entries get fully overwritten by fill_k).
  hipMemsetAsync(d_ws, 0, (size_t)WS_ZERO_N * sizeof(int), stream);

  bn_stats_k<<<512, 256, 0, stream>>>(vf, N_VAR, stats);
  bn_stats_k<<<512, 256, 0, stream>>>(cf, N_CSTR, stats + 128);
  bn_finalize_k<<<1, 128, 0, stream>>>(stats, gn, bn, gc, bc, ab);

  hist_k<<<(NEDGE + 255) / 256, 256, 0, stream>>>(es, ed, deg_node, deg_cstr);
  scan_k<<<2, 1024, 0, stream>>>(wsi);
  fill_k<<<(NEDGE + 255) / 256, 256, 0, stream>>>(es, ed, ea, cur_node, cur_cstr,
                                                 ent_node, ent_cstr);

  // Node side: dst = var nodes, src = cstr nodes.
  gather_out_k<<<1280, 256, 0, stream>>>(vf, cf, ent_node, off_node, ab, ab + 128,
                                         n_rel_w, n_rel_b, n_root_w, out, N_VAR);
  // Cstr side: dst = cstr nodes, src = var nodes.
  gather_out_k<<<640, 256, 0, stream>>>(cf, vf, ent_cstr, off_cstr, ab + 128, ab,
                                        c_rel_w, c_rel_b, c_root_w, out + 6400000,
                                        N_CSTR);
}

// Round 3
// 792.193 us; speedup vs baseline: 1.5606x; 1.5606x over previous
//
#include <hip/hip_runtime.h>

#define N_VAR   100000
#define N_CSTR  50000
#define NEDGE   1000000
#define DIM     64

// ---------------------------------------------------------------------------
// Workspace layout (4-byte units), total ~17.8 MB:
//   0:        deg_node   100000 (int)   -- zeroed
//   100000:   deg_cstr    50000 (int)   -- zeroed
//   150000:   stats         256 (float) -- zeroed
//   150256:   ab            256 (float: a_n,b_n,a_c,b_c)
//   150512:   off_node   100001 (int)
//   250513:   off_cstr    50001 (int)
//   300514:   cur_node   100000 (int)
//   400514:   cur_cstr    50000 (int)
//   450514:   ent_node  1000000 (int2)  [2M ints]
//   2450514:  ent_cstr  1000000 (int2)  [2M ints]
// agg rows are NOT in ws: gather writes them straight into d_out and out_k
// rewrites d_out in place (each output row depends only on its own agg row).
// ---------------------------------------------------------------------------
#define OFF_DEG_N   0
#define OFF_DEG_C   100000
#define OFF_STATS   150000
#define OFF_AB      150256
#define OFF_OFF_N   150512
#define OFF_OFF_C   250513
#define OFF_CUR_N   300514
#define OFF_CUR_C   400514
#define OFF_ENT_N   450514
#define OFF_ENT_C   2450514
#define WS_ZERO_N   150512   // ints to zero (deg_n, deg_c, stats)

// ---------------------------------------------------------------------------
// BN column stats: partial sum/sumsq per column -> atomics into stats.
// ---------------------------------------------------------------------------
__global__ __launch_bounds__(256) void bn_stats_k(const float* __restrict__ x, int n,
                                                  float* __restrict__ stats) {
  int c = threadIdx.x & 63;
  int rg = threadIdx.x >> 6;
  float s = 0.f, q = 0.f;
  for (int r = blockIdx.x * 4 + rg; r < n; r += gridDim.x * 4) {
    float v = x[r * DIM + c];
    s += v;
    q += v * v;
  }
  __shared__ float sb[256], qb[256];
  sb[threadIdx.x] = s;
  qb[threadIdx.x] = q;
  __syncthreads();
  if (rg == 0) {
    s = sb[c] + sb[c + 64] + sb[c + 128] + sb[c + 192];
    q = qb[c] + qb[c + 64] + qb[c + 128] + qb[c + 192];
    atomicAdd(&stats[c], s);
    atomicAdd(&stats[64 + c], q);
  }
}

__global__ void bn_finalize_k(const float* __restrict__ stats,
                              const float* __restrict__ gn, const float* __restrict__ bn,
                              const float* __restrict__ gc, const float* __restrict__ bc,
                              float* __restrict__ ab) {
  int t = threadIdx.x;  // 0..127
  int c = t & 63;
  bool isC = t >= 64;
  const float* st = stats + (isC ? 128 : 0);
  float n = isC ? (float)N_CSTR : (float)N_VAR;
  float mean = st[c] / n;
  float var = st[64 + c] / n - mean * mean;
  float g = isC ? gc[c] : gn[c];
  float be = isC ? bc[c] : bn[c];
  float a = g * rsqrtf(var + 1e-5f);
  float b = be - mean * a;
  float* o = ab + (isC ? 128 : 0);
  o[c] = a;
  o[64 + c] = b;
}

// ---------------------------------------------------------------------------
// Degree histogram (int atomics, L2-resident counters).
// ---------------------------------------------------------------------------
__global__ __launch_bounds__(256) void hist_k(const int* __restrict__ esrc,
                                              const int* __restrict__ edst,
                                              int* __restrict__ deg_node,
                                              int* __restrict__ deg_cstr) {
  int e = blockIdx.x * blockDim.x + threadIdx.x;
  if (e < NEDGE) {
    atomicAdd(&deg_node[edst[e]], 1);
    atomicAdd(&deg_cstr[esrc[e]], 1);
  }
}

// ---------------------------------------------------------------------------
// Exclusive scan; block 0: node arrays, block 1: cstr arrays.
// ---------------------------------------------------------------------------
__global__ __launch_bounds__(1024) void scan_k(int* __restrict__ ws) {
  const int* deg = (blockIdx.x == 0) ? ws + OFF_DEG_N : ws + OFF_DEG_C;
  int* off = (blockIdx.x == 0) ? ws + OFF_OFF_N : ws + OFF_OFF_C;
  int* cur = (blockIdx.x == 0) ? ws + OFF_CUR_N : ws + OFF_CUR_C;
  int n = (blockIdx.x == 0) ? N_VAR : N_CSTR;
  int t = threadIdx.x;
  int chunk = (n + 1023) / 1024;
  int lo = t * chunk, hi = min(n, lo + chunk);
  int s = 0;
  for (int i = lo; i < hi; ++i) s += deg[i];
  __shared__ int sb[1024];
  sb[t] = s;
  __syncthreads();
  for (int d = 1; d < 1024; d <<= 1) {
    int v = (t >= d) ? sb[t - d] : 0;
    __syncthreads();
    sb[t] += v;
    __syncthreads();
  }
  int run = sb[t] - s;
  for (int i = lo; i < hi; ++i) {
    off[i] = run;
    cur[i] = run;
    run += deg[i];
  }
  if (t == 0) off[n] = NEDGE;
}

// ---------------------------------------------------------------------------
// Fill CSR buckets.
// ---------------------------------------------------------------------------
__global__ __launch_bounds__(256) void fill_k(const int* __restrict__ esrc,
                                              const int* __restrict__ edst,
                                              const float* __restrict__ eattr,
                                              int* __restrict__ cur_node,
                                              int* __restrict__ cur_cstr,
                                              int2* __restrict__ ent_node,
                                              int2* __restrict__ ent_cstr) {
  int e = blockIdx.x * blockDim.x + threadIdx.x;
  if (e < NEDGE) {
    int s = esrc[e];
    int d = edst[e];
    int wb = __float_as_int(eattr[e]);
    int p0 = atomicAdd(&cur_node[d], 1);
    ent_node[p0] = make_int2(s, wb);
    int p1 = atomicAdd(&cur_cstr[s], 1);
    ent_cstr[p1] = make_int2(d, wb);
  }
}

// ---------------------------------------------------------------------------
// Gather: one wave per destination row, lane = column. Unrolled by 4 so four
// independent 256 B row-gathers are in flight per wave. Row id is pinned to
// an SGPR (readfirstlane) so off/ent loads go scalar. Tiny VGPR footprint ->
// 8 waves/SIMD. Writes the mean-aggregated, BN-applied message row to agg
// (which aliases d_out).
// ---------------------------------------------------------------------------
__global__ __launch_bounds__(256) void gather_k(
    const float* __restrict__ srcf, const int2* __restrict__ ent,
    const int* __restrict__ off, const float* __restrict__ ab_src,
    float* __restrict__ agg, int n) {
  int lane = threadIdx.x & 63;
  float a_s = ab_src[lane], b_s = ab_src[64 + lane];
  int r = __builtin_amdgcn_readfirstlane((blockIdx.x * blockDim.x + threadIdx.x) >> 6);
  if (r >= n) return;
  int beg = off[r], end = off[r + 1];
  float acc = 0.f;
  int e = beg;
  for (; e + 4 <= end; e += 4) {
    int2 e0 = ent[e], e1 = ent[e + 1], e2 = ent[e + 2], e3 = ent[e + 3];
    float v0 = srcf[e0.x * DIM + lane];
    float v1 = srcf[e1.x * DIM + lane];
    float v2 = srcf[e2.x * DIM + lane];
    float v3 = srcf[e3.x * DIM + lane];
    acc = fmaf(fmaf(v0, a_s, b_s), __int_as_float(e0.y), acc);
    acc = fmaf(fmaf(v1, a_s, b_s), __int_as_float(e1.y), acc);
    acc = fmaf(fmaf(v2, a_s, b_s), __int_as_float(e2.y), acc);
    acc = fmaf(fmaf(v3, a_s, b_s), __int_as_float(e3.y), acc);
  }
  for (; e < end; ++e) {
    int2 e0 = ent[e];
    acc = fmaf(fmaf(srcf[e0.x * DIM + lane], a_s, b_s), __int_as_float(e0.y), acc);
  }
  agg[r * DIM + lane] = acc / fmaxf((float)(end - beg), 1.f);
}

// ---------------------------------------------------------------------------
// Output GEMM + epilogue, in place on io (= d_out region holding agg rows):
//   out[r][c] = relu( agg[r] . w_rel[c][:] + b_rel[c] + xv . w_root[c][:] + xv[c] )
// Weights in registers (lane c holds w_rel[c][:], w_root[c][:]). Row values
// are broadcast with v_readlane (pure VALU) instead of an LDS round-trip:
// LDS b128 reads at ~12 cyc/CU would cost ~94 us across both sides.
// ---------------------------------------------------------------------------
__global__ __launch_bounds__(256) void out_k(
    const float* __restrict__ raw, const float* __restrict__ ab,
    const float* __restrict__ w_rel, const float* __restrict__ b_rel,
    const float* __restrict__ w_root, float* __restrict__ io, int n) {
  int lane = threadIdx.x & 63;
  float a = ab[lane], b = ab[64 + lane];
  float brel = b_rel[lane];
  float4 wr[16], wo[16];
#pragma unroll
  for (int i = 0; i < 16; ++i) {
    wr[i] = reinterpret_cast<const float4*>(w_rel + lane * DIM)[i];
    wo[i] = reinterpret_cast<const float4*>(w_root + lane * DIM)[i];
  }
  int wave = (blockIdx.x * blockDim.x + threadIdx.x) >> 6;
  int nw = (gridDim.x * blockDim.x) >> 6;
  for (int r = wave; r < n; r += nw) {
    float av = io[r * DIM + lane];
    float xv = fmaf(raw[r * DIM + lane], a, b);
    int avi = __float_as_int(av);
    int xvi = __float_as_int(xv);
    float acc0 = 0.f, acc1 = 0.f, acc2 = 0.f, acc3 = 0.f;
#pragma unroll
    for (int i = 0; i < 16; ++i) {
      acc0 = fmaf(__int_as_float(__builtin_amdgcn_readlane(avi, 4 * i + 0)), wr[i].x, acc0);
      acc1 = fmaf(__int_as_float(__builtin_amdgcn_readlane(avi, 4 * i + 1)), wr[i].y, acc1);
      acc2 = fmaf(__int_as_float(__builtin_amdgcn_readlane(avi, 4 * i + 2)), wr[i].z, acc2);
      acc3 = fmaf(__int_as_float(__builtin_amdgcn_readlane(avi, 4 * i + 3)), wr[i].w, acc3);
      acc0 = fmaf(__int_as_float(__builtin_amdgcn_readlane(xvi, 4 * i + 0)), wo[i].x, acc0);
      acc1 = fmaf(__int_as_float(__builtin_amdgcn_readlane(xvi, 4 * i + 1)), wo[i].y, acc1);
      acc2 = fmaf(__int_as_float(__builtin_amdgcn_readlane(xvi, 4 * i + 2)), wo[i].z, acc2);
      acc3 = fmaf(__int_as_float(__builtin_amdgcn_readlane(xvi, 4 * i + 3)), wo[i].w, acc3);
    }
    io[r * DIM + lane] = fmaxf((acc0 + acc1) + (acc2 + acc3) + brel + xv, 0.f);
  }
}

extern "C" void kernel_launch(void* const* d_in, const int* in_sizes, int n_in,
                              void* d_out, int out_size, void* d_ws, size_t ws_size,
                              hipStream_t stream) {
  const float* vf = (const float*)d_in[0];
  const float* cf = (const float*)d_in[1];
  const int* es = (const int*)d_in[2];
  const int* ed = (const int*)d_in[3];
  const float* ea = (const float*)d_in[4];
  const float* gn = (const float*)d_in[5];
  const float* bn = (const float*)d_in[6];
  const float* gc = (const float*)d_in[7];
  const float* bc = (const float*)d_in[8];
  const float* n_rel_w = (const float*)d_in[9];
  const float* n_rel_b = (const float*)d_in[10];
  const float* n_root_w = (const float*)d_in[11];
  const float* c_rel_w = (const float*)d_in[12];
  const float* c_rel_b = (const float*)d_in[13];
  const float* c_root_w = (const float*)d_in[14];
  float* out = (float*)d_out;
  int* wsi = (int*)d_ws;
  float* wsf = (float*)d_ws;

  int* deg_node = wsi + OFF_DEG_N;
  int* deg_cstr = wsi + OFF_DEG_C;
  float* stats = wsf + OFF_STATS;
  float* ab = wsf + OFF_AB;
  int* off_node = wsi + OFF_OFF_N;
  int* off_cstr = wsi + OFF_OFF_C;
  int* cur_node = wsi + OFF_CUR_N;
  int* cur_cstr = wsi + OFF_CUR_C;
  int2* ent_node = (int2*)(wsi + OFF_ENT_N);
  int2* ent_cstr = (int2*)(wsi + OFF_ENT_C);

  float* agg_node = out;            // d_out rows reused as agg scratch
  float* agg_cstr = out + 6400000;

  hipMemsetAsync(d_ws, 0, (size_t)WS_ZERO_N * sizeof(int), stream);

  bn_stats_k<<<512, 256, 0, stream>>>(vf, N_VAR, stats);
  bn_stats_k<<<512, 256, 0, stream>>>(cf, N_CSTR, stats + 128);
  bn_finalize_k<<<1, 128, 0, stream>>>(stats, gn, bn, gc, bc, ab);

  hist_k<<<(NEDGE + 255) / 256, 256, 0, stream>>>(es, ed, deg_node, deg_cstr);
  scan_k<<<2, 1024, 0, stream>>>(wsi);
  fill_k<<<(NEDGE + 255) / 256, 256, 0, stream>>>(es, ed, ea, cur_node, cur_cstr,
                                                 ent_node, ent_cstr);

  // One wave per row: grid = ceil(n/4) blocks of 4 waves.
  gather_k<<<(N_VAR + 3) / 4, 256, 0, stream>>>(cf, ent_node, off_node, ab + 128,
                                                agg_node, N_VAR);
  gather_k<<<(N_CSTR + 3) / 4, 256, 0, stream>>>(vf, ent_cstr, off_cstr, ab,
                                                 agg_cstr, N_CSTR);

  out_k<<<1024, 256, 0, stream>>>(vf, ab, n_rel_w, n_rel_b, n_root_w, agg_node, N_VAR);
  out_k<<<512, 256, 0, stream>>>(cf, ab + 128, c_rel_w, c_rel_b, c_root_w, agg_cstr,
                                 N_CSTR);
}

// Round 4
// 574.322 us; speedup vs baseline: 2.1526x; 1.3794x over previous
//
#include <hip/hip_runtime.h>

#define N_VAR   100000
#define N_CSTR  50000
#define NEDGE   1000000
#define DIM     64

// Two-level scan geometry: 1024 elements per block.
#define NB_N 98    // ceil(100000/1024)
#define NB_C 49    // ceil(50000/1024)
#define NB_T 147

// ---------------------------------------------------------------------------
// Workspace layout (4-byte units), all arrays 16B-aligned, total ~17.8 MB:
//   0:        deg_node   100000 (int)   -- zeroed
//   100000:   deg_cstr    50000 (int)   -- zeroed
//   150000:   stats         256 (float) -- zeroed
//   150256:   ab            256 (float: a_n,b_n,a_c,b_c)
//   150512:   off_node   100001 (int)
//   250516:   off_cstr    50001 (int)
//   300520:   cur_node   100000 (int)
//   400520:   cur_cstr    50000 (int)
//   450520:   bsum          160 (int, per-block sums)
//   450680:   bpref         160 (int, scanned block prefixes)
//   450840:   ent_node  1000000 (int2)
//   2450840:  ent_cstr  1000000 (int2)
// agg rows live in d_out; out_k rewrites d_out in place.
// ---------------------------------------------------------------------------
#define OFF_DEG_N   0
#define OFF_DEG_C   100000
#define OFF_STATS   150000
#define OFF_AB      150256
#define OFF_OFF_N   150512
#define OFF_OFF_C   250516
#define OFF_CUR_N   300520
#define OFF_CUR_C   400520
#define OFF_BSUM    450520
#define OFF_BPREF   450680
#define OFF_ENT_N   450840
#define OFF_ENT_C   2450840
#define WS_ZERO_N   150512   // ints to zero (deg_n, deg_c, stats)

// ---------------------------------------------------------------------------
// BN column stats.
// ---------------------------------------------------------------------------
__global__ __launch_bounds__(256) void bn_stats_k(const float* __restrict__ x, int n,
                                                  float* __restrict__ stats) {
  int c = threadIdx.x & 63;
  int rg = threadIdx.x >> 6;
  float s = 0.f, q = 0.f;
  for (int r = blockIdx.x * 4 + rg; r < n; r += gridDim.x * 4) {
    float v = x[r * DIM + c];
    s += v;
    q += v * v;
  }
  __shared__ float sb[256], qb[256];
  sb[threadIdx.x] = s;
  qb[threadIdx.x] = q;
  __syncthreads();
  if (rg == 0) {
    s = sb[c] + sb[c + 64] + sb[c + 128] + sb[c + 192];
    q = qb[c] + qb[c + 64] + qb[c + 128] + qb[c + 192];
    atomicAdd(&stats[c], s);
    atomicAdd(&stats[64 + c], q);
  }
}

__global__ void bn_finalize_k(const float* __restrict__ stats,
                              const float* __restrict__ gn, const float* __restrict__ bn,
                              const float* __restrict__ gc, const float* __restrict__ bc,
                              float* __restrict__ ab) {
  int t = threadIdx.x;  // 0..127
  int c = t & 63;
  bool isC = t >= 64;
  const float* st = stats + (isC ? 128 : 0);
  float n = isC ? (float)N_CSTR : (float)N_VAR;
  float mean = st[c] / n;
  float var = st[64 + c] / n - mean * mean;
  float g = isC ? gc[c] : gn[c];
  float be = isC ? bc[c] : bn[c];
  float a = g * rsqrtf(var + 1e-5f);
  float b = be - mean * a;
  float* o = ab + (isC ? 128 : 0);
  o[c] = a;
  o[64 + c] = b;
}

// ---------------------------------------------------------------------------
// Degree histogram (int atomics).
// ---------------------------------------------------------------------------
__global__ __launch_bounds__(256) void hist_k(const int* __restrict__ esrc,
                                              const int* __restrict__ edst,
                                              int* __restrict__ deg_node,
                                              int* __restrict__ deg_cstr) {
  int e = blockIdx.x * blockDim.x + threadIdx.x;
  if (e < NEDGE) {
    atomicAdd(&deg_node[edst[e]], 1);
    atomicAdd(&deg_cstr[esrc[e]], 1);
  }
}

// ---------------------------------------------------------------------------
// Two-level scan, phase 1: per-block (1024-element) sums -> bsum[147].
// Blocks [0,98) cover deg_node, [98,147) cover deg_cstr.
// ---------------------------------------------------------------------------
__global__ __launch_bounds__(256) void scan_part_k(int* __restrict__ ws) {
  int b = blockIdx.x;
  int seg = (b >= NB_N);
  const int* deg = ws + (seg ? OFF_DEG_C : OFF_DEG_N);
  int n = seg ? N_CSTR : N_VAR;
  int lb = seg ? b - NB_N : b;
  int base = lb * 1024 + threadIdx.x * 4;
  int s = 0;
  if (base + 4 <= n) {
    int4 v = *reinterpret_cast<const int4*>(deg + base);
    s = v.x + v.y + v.z + v.w;
  } else {
    for (int i = base; i < n; ++i) s += deg[i];
  }
  __shared__ int sb[256];
  sb[threadIdx.x] = s;
  __syncthreads();
  for (int d = 128; d > 0; d >>= 1) {
    if (threadIdx.x < d) sb[threadIdx.x] += sb[threadIdx.x + d];
    __syncthreads();
  }
  if (threadIdx.x == 0) ws[OFF_BSUM + b] = sb[0];
}

// ---------------------------------------------------------------------------
// Phase 2: one block scans the 147 block sums (two independent segments).
// Lanes 0..127 scan node sums, 128..255 scan cstr sums. Also seeds off[n].
// ---------------------------------------------------------------------------
__global__ __launch_bounds__(256) void scan_meta_k(int* __restrict__ ws) {
  int t = threadIdx.x;
  int seg = t >> 7;
  int lt = t & 127;
  int nb = seg ? NB_C : NB_N;
  int v = (lt < nb) ? ws[OFF_BSUM + (seg ? NB_N : 0) + lt] : 0;
  __shared__ int sb[256];
  sb[t] = v;
  __syncthreads();
  for (int d = 1; d < 128; d <<= 1) {
    int u = (lt >= d) ? sb[t - d] : 0;
    __syncthreads();
    sb[t] += u;
    __syncthreads();
  }
  if (lt < nb) ws[OFF_BPREF + (seg ? NB_N : 0) + lt] = sb[t] - v;
  if (t == 0) {
    ws[OFF_OFF_N + N_VAR] = NEDGE;
    ws[OFF_OFF_C + N_CSTR] = NEDGE;
  }
}

// ---------------------------------------------------------------------------
// Phase 3: per-block local exclusive scan + block prefix -> off[] and cur[].
// ---------------------------------------------------------------------------
__global__ __launch_bounds__(256) void scan_apply_k(int* __restrict__ ws) {
  int b = blockIdx.x;
  int seg = (b >= NB_N);
  const int* deg = ws + (seg ? OFF_DEG_C : OFF_DEG_N);
  int* off = ws + (seg ? OFF_OFF_C : OFF_OFF_N);
  int* cur = ws + (seg ? OFF_CUR_C : OFF_CUR_N);
  int n = seg ? N_CSTR : N_VAR;
  int lb = seg ? b - NB_N : b;
  int base = lb * 1024 + threadIdx.x * 4;
  int4 v = make_int4(0, 0, 0, 0);
  if (base + 4 <= n) {
    v = *reinterpret_cast<const int4*>(deg + base);
  } else {
    if (base < n) v.x = deg[base];
    if (base + 1 < n) v.y = deg[base + 1];
    if (base + 2 < n) v.z = deg[base + 2];
    if (base + 3 < n) v.w = deg[base + 3];
  }
  int s = v.x + v.y + v.z + v.w;
  __shared__ int sb[256];
  sb[threadIdx.x] = s;
  __syncthreads();
  for (int d = 1; d < 256; d <<= 1) {
    int u = (threadIdx.x >= d) ? sb[threadIdx.x - d] : 0;
    __syncthreads();
    sb[threadIdx.x] += u;
    __syncthreads();
  }
  int excl = sb[threadIdx.x] - s + ws[OFF_BPREF + b];
  int4 o;
  o.x = excl;
  o.y = o.x + v.x;
  o.z = o.y + v.y;
  o.w = o.z + v.z;
  if (base + 4 <= n) {
    *reinterpret_cast<int4*>(off + base) = o;
    *reinterpret_cast<int4*>(cur + base) = o;
  } else {
    if (base < n)     { off[base] = o.x;     cur[base] = o.x; }
    if (base + 1 < n) { off[base + 1] = o.y; cur[base + 1] = o.y; }
    if (base + 2 < n) { off[base + 2] = o.z; cur[base + 2] = o.z; }
    if (base + 3 < n) { off[base + 3] = o.w; cur[base + 3] = o.w; }
  }
}

// ---------------------------------------------------------------------------
// Fill CSR buckets.
// ---------------------------------------------------------------------------
__global__ __launch_bounds__(256) void fill_k(const int* __restrict__ esrc,
                                              const int* __restrict__ edst,
                                              const float* __restrict__ eattr,
                                              int* __restrict__ cur_node,
                                              int* __restrict__ cur_cstr,
                                              int2* __restrict__ ent_node,
                                              int2* __restrict__ ent_cstr) {
  int e = blockIdx.x * blockDim.x + threadIdx.x;
  if (e < NEDGE) {
    int s = esrc[e];
    int d = edst[e];
    int wb = __float_as_int(eattr[e]);
    int p0 = atomicAdd(&cur_node[d], 1);
    ent_node[p0] = make_int2(s, wb);
    int p1 = atomicAdd(&cur_cstr[s], 1);
    ent_cstr[p1] = make_int2(d, wb);
  }
}

// ---------------------------------------------------------------------------
// Gather: one wave per destination row, lane = column, unroll-4 gathers.
// ---------------------------------------------------------------------------
__global__ __launch_bounds__(256) void gather_k(
    const float* __restrict__ srcf, const int2* __restrict__ ent,
    const int* __restrict__ off, const float* __restrict__ ab_src,
    float* __restrict__ agg, int n) {
  int lane = threadIdx.x & 63;
  float a_s = ab_src[lane], b_s = ab_src[64 + lane];
  int r = __builtin_amdgcn_readfirstlane((blockIdx.x * blockDim.x + threadIdx.x) >> 6);
  if (r >= n) return;
  int beg = off[r], end = off[r + 1];
  float acc = 0.f;
  int e = beg;
  for (; e + 4 <= end; e += 4) {
    int2 e0 = ent[e], e1 = ent[e + 1], e2 = ent[e + 2], e3 = ent[e + 3];
    float v0 = srcf[e0.x * DIM + lane];
    float v1 = srcf[e1.x * DIM + lane];
    float v2 = srcf[e2.x * DIM + lane];
    float v3 = srcf[e3.x * DIM + lane];
    acc = fmaf(fmaf(v0, a_s, b_s), __int_as_float(e0.y), acc);
    acc = fmaf(fmaf(v1, a_s, b_s), __int_as_float(e1.y), acc);
    acc = fmaf(fmaf(v2, a_s, b_s), __int_as_float(e2.y), acc);
    acc = fmaf(fmaf(v3, a_s, b_s), __int_as_float(e3.y), acc);
  }
  for (; e < end; ++e) {
    int2 e0 = ent[e];
    acc = fmaf(fmaf(srcf[e0.x * DIM + lane], a_s, b_s), __int_as_float(e0.y), acc);
  }
  agg[r * DIM + lane] = acc / fmaxf((float)(end - beg), 1.f);
}

// ---------------------------------------------------------------------------
// Output GEMM + epilogue in place; weights in registers, readlane broadcast.
// ---------------------------------------------------------------------------
__global__ __launch_bounds__(256) void out_k(
    const float* __restrict__ raw, const float* __restrict__ ab,
    const float* __restrict__ w_rel, const float* __restrict__ b_rel,
    const float* __restrict__ w_root, float* __restrict__ io, int n) {
  int lane = threadIdx.x & 63;
  float a = ab[lane], b = ab[64 + lane];
  float brel = b_rel[lane];
  float4 wr[16], wo[16];
#pragma unroll
  for (int i = 0; i < 16; ++i) {
    wr[i] = reinterpret_cast<const float4*>(w_rel + lane * DIM)[i];
    wo[i] = reinterpret_cast<const float4*>(w_root + lane * DIM)[i];
  }
  int wave = (blockIdx.x * blockDim.x + threadIdx.x) >> 6;
  int nw = (gridDim.x * blockDim.x) >> 6;
  for (int r = wave; r < n; r += nw) {
    float av = io[r * DIM + lane];
    float xv = fmaf(raw[r * DIM + lane], a, b);
    int avi = __float_as_int(av);
    int xvi = __float_as_int(xv);
    float acc0 = 0.f, acc1 = 0.f, acc2 = 0.f, acc3 = 0.f;
#pragma unroll
    for (int i = 0; i < 16; ++i) {
      acc0 = fmaf(__int_as_float(__builtin_amdgcn_readlane(avi, 4 * i + 0)), wr[i].x, acc0);
      acc1 = fmaf(__int_as_float(__builtin_amdgcn_readlane(avi, 4 * i + 1)), wr[i].y, acc1);
      acc2 = fmaf(__int_as_float(__builtin_amdgcn_readlane(avi, 4 * i + 2)), wr[i].z, acc2);
      acc3 = fmaf(__int_as_float(__builtin_amdgcn_readlane(avi, 4 * i + 3)), wr[i].w, acc3);
      acc0 = fmaf(__int_as_float(__builtin_amdgcn_readlane(xvi, 4 * i + 0)), wo[i].x, acc0);
      acc1 = fmaf(__int_as_float(__builtin_amdgcn_readlane(xvi, 4 * i + 1)), wo[i].y, acc1);
      acc2 = fmaf(__int_as_float(__builtin_amdgcn_readlane(xvi, 4 * i + 2)), wo[i].z, acc2);
      acc3 = fmaf(__int_as_float(__builtin_amdgcn_readlane(xvi, 4 * i + 3)), wo[i].w, acc3);
    }
    io[r * DIM + lane] = fmaxf((acc0 + acc1) + (acc2 + acc3) + brel + xv, 0.f);
  }
}

extern "C" void kernel_launch(void* const* d_in, const int* in_sizes, int n_in,
                              void* d_out, int out_size, void* d_ws, size_t ws_size,
                              hipStream_t stream) {
  const float* vf = (const float*)d_in[0];
  const float* cf = (const float*)d_in[1];
  const int* es = (const int*)d_in[2];
  const int* ed = (const int*)d_in[3];
  const float* ea = (const float*)d_in[4];
  const float* gn = (const float*)d_in[5];
  const float* bn = (const float*)d_in[6];
  const float* gc = (const float*)d_in[7];
  const float* bc = (const float*)d_in[8];
  const float* n_rel_w = (const float*)d_in[9];
  const float* n_rel_b = (const float*)d_in[10];
  const float* n_root_w = (const float*)d_in[11];
  const float* c_rel_w = (const float*)d_in[12];
  const float* c_rel_b = (const float*)d_in[13];
  const float* c_root_w = (const float*)d_in[14];
  float* out = (float*)d_out;
  int* wsi = (int*)d_ws;
  float* wsf = (float*)d_ws;

  int* deg_node = wsi + OFF_DEG_N;
  int* deg_cstr = wsi + OFF_DEG_C;
  float* stats = wsf + OFF_STATS;
  float* ab = wsf + OFF_AB;
  int* off_node = wsi + OFF_OFF_N;
  int* off_cstr = wsi + OFF_OFF_C;
  int* cur_node = wsi + OFF_CUR_N;
  int* cur_cstr = wsi + OFF_CUR_C;
  int2* ent_node = (int2*)(wsi + OFF_ENT_N);
  int2* ent_cstr = (int2*)(wsi + OFF_ENT_C);

  float* agg_node = out;            // d_out rows reused as agg scratch
  float* agg_cstr = out + 6400000;

  hipMemsetAsync(d_ws, 0, (size_t)WS_ZERO_N * sizeof(int), stream);

  bn_stats_k<<<512, 256, 0, stream>>>(vf, N_VAR, stats);
  bn_stats_k<<<512, 256, 0, stream>>>(cf, N_CSTR, stats + 128);
  bn_finalize_k<<<1, 128, 0, stream>>>(stats, gn, bn, gc, bc, ab);

  hist_k<<<(NEDGE + 255) / 256, 256, 0, stream>>>(es, ed, deg_node, deg_cstr);
  scan_part_k<<<NB_T, 256, 0, stream>>>(wsi);
  scan_meta_k<<<1, 256, 0, stream>>>(wsi);
  scan_apply_k<<<NB_T, 256, 0, stream>>>(wsi);
  fill_k<<<(NEDGE + 255) / 256, 256, 0, stream>>>(es, ed, ea, cur_node, cur_cstr,
                                                 ent_node, ent_cstr);

  gather_k<<<(N_VAR + 3) / 4, 256, 0, stream>>>(cf, ent_node, off_node, ab + 128,
                                                agg_node, N_VAR);
  gather_k<<<(N_CSTR + 3) / 4, 256, 0, stream>>>(vf, ent_cstr, off_cstr, ab,
                                                 agg_cstr, N_CSTR);

  out_k<<<1024, 256, 0, stream>>>(vf, ab, n_rel_w, n_rel_b, n_root_w, agg_node, N_VAR);
  out_k<<<512, 256, 0, stream>>>(cf, ab + 128, c_rel_w, c_rel_b, c_root_w, agg_cstr,
                                 N_CSTR);
}

// Round 5
// 568.155 us; speedup vs baseline: 2.1759x; 1.0109x over previous
//
#include <hip/hip_runtime.h>

#define N_VAR   100000
#define N_CSTR  50000
#define NEDGE   1000000
#define DIM     64

// Two-level scan geometry: 1024 elements per block.
#define NB_N 98    // ceil(100000/1024)
#define NB_C 49    // ceil(50000/1024)
#define NB_T 147

// ---------------------------------------------------------------------------
// Workspace layout (4-byte units), all arrays 16B-aligned, total ~17.8 MB:
//   0:        deg_node   100000 (int)   -- zeroed
//   100000:   deg_cstr    50000 (int)   -- zeroed
//   150000:   stats         256 (float) -- zeroed
//   150256:   ab            256 (float: a_n,b_n,a_c,b_c)
//   150512:   off_node   100001 (int)
//   250516:   off_cstr    50001 (int)
//   300520:   cur_node   100000 (int)
//   400520:   cur_cstr    50000 (int)
//   450520:   bsum          160 (int)
//   450680:   bpref         160 (int)
//   450840:   ent_node  1000000 (int2)
//   2450840:  ent_cstr  1000000 (int2)
// agg rows live in d_out; out_k rewrites d_out in place.
// ---------------------------------------------------------------------------
#define OFF_DEG_N   0
#define OFF_DEG_C   100000
#define OFF_STATS   150000
#define OFF_AB      150256
#define OFF_OFF_N   150512
#define OFF_OFF_C   250516
#define OFF_CUR_N   300520
#define OFF_CUR_C   400520
#define OFF_BSUM    450520
#define OFF_BPREF   450680
#define OFF_ENT_N   450840
#define OFF_ENT_C   2450840
#define WS_ZERO_N   150512   // ints to zero (deg_n, deg_c, stats)

// ---------------------------------------------------------------------------
// BN column stats.
// ---------------------------------------------------------------------------
__global__ __launch_bounds__(256) void bn_stats_k(const float* __restrict__ x, int n,
                                                  float* __restrict__ stats) {
  int c = threadIdx.x & 63;
  int rg = threadIdx.x >> 6;
  float s = 0.f, q = 0.f;
  for (int r = blockIdx.x * 4 + rg; r < n; r += gridDim.x * 4) {
    float v = x[r * DIM + c];
    s += v;
    q += v * v;
  }
  __shared__ float sb[256], qb[256];
  sb[threadIdx.x] = s;
  qb[threadIdx.x] = q;
  __syncthreads();
  if (rg == 0) {
    s = sb[c] + sb[c + 64] + sb[c + 128] + sb[c + 192];
    q = qb[c] + qb[c + 64] + qb[c + 128] + qb[c + 192];
    atomicAdd(&stats[c], s);
    atomicAdd(&stats[64 + c], q);
  }
}

__global__ void bn_finalize_k(const float* __restrict__ stats,
                              const float* __restrict__ gn, const float* __restrict__ bn,
                              const float* __restrict__ gc, const float* __restrict__ bc,
                              float* __restrict__ ab) {
  int t = threadIdx.x;  // 0..127
  int c = t & 63;
  bool isC = t >= 64;
  const float* st = stats + (isC ? 128 : 0);
  float n = isC ? (float)N_CSTR : (float)N_VAR;
  float mean = st[c] / n;
  float var = st[64 + c] / n - mean * mean;
  float g = isC ? gc[c] : gn[c];
  float be = isC ? bc[c] : bn[c];
  float a = g * rsqrtf(var + 1e-5f);
  float b = be - mean * a;
  float* o = ab + (isC ? 128 : 0);
  o[c] = a;
  o[64 + c] = b;
}

// ---------------------------------------------------------------------------
// Degree histogram: 4 edges per thread, vector loads, fire-and-forget atomics.
// ---------------------------------------------------------------------------
__global__ __launch_bounds__(256) void hist_k(const int4* __restrict__ es4,
                                              const int4* __restrict__ ed4,
                                              int* __restrict__ deg_node,
                                              int* __restrict__ deg_cstr) {
  int g = blockIdx.x * blockDim.x + threadIdx.x;
  if (g < NEDGE / 4) {
    int4 d = ed4[g];
    int4 s = es4[g];
    atomicAdd(&deg_node[d.x], 1);
    atomicAdd(&deg_node[d.y], 1);
    atomicAdd(&deg_node[d.z], 1);
    atomicAdd(&deg_node[d.w], 1);
    atomicAdd(&deg_cstr[s.x], 1);
    atomicAdd(&deg_cstr[s.y], 1);
    atomicAdd(&deg_cstr[s.z], 1);
    atomicAdd(&deg_cstr[s.w], 1);
  }
}

// ---------------------------------------------------------------------------
// Two-level scan, phase 1: per-block (1024-element) sums -> bsum[147].
// ---------------------------------------------------------------------------
__global__ __launch_bounds__(256) void scan_part_k(int* __restrict__ ws) {
  int b = blockIdx.x;
  int seg = (b >= NB_N);
  const int* deg = ws + (seg ? OFF_DEG_C : OFF_DEG_N);
  int n = seg ? N_CSTR : N_VAR;
  int lb = seg ? b - NB_N : b;
  int base = lb * 1024 + threadIdx.x * 4;
  int s = 0;
  if (base + 4 <= n) {
    int4 v = *reinterpret_cast<const int4*>(deg + base);
    s = v.x + v.y + v.z + v.w;
  } else {
    for (int i = base; i < n; ++i) s += deg[i];
  }
  __shared__ int sb[256];
  sb[threadIdx.x] = s;
  __syncthreads();
  for (int d = 128; d > 0; d >>= 1) {
    if (threadIdx.x < d) sb[threadIdx.x] += sb[threadIdx.x + d];
    __syncthreads();
  }
  if (threadIdx.x == 0) ws[OFF_BSUM + b] = sb[0];
}

// ---------------------------------------------------------------------------
// Phase 2: one block scans the 147 block sums; seeds off[n].
// ---------------------------------------------------------------------------
__global__ __launch_bounds__(256) void scan_meta_k(int* __restrict__ ws) {
  int t = threadIdx.x;
  int seg = t >> 7;
  int lt = t & 127;
  int nb = seg ? NB_C : NB_N;
  int v = (lt < nb) ? ws[OFF_BSUM + (seg ? NB_N : 0) + lt] : 0;
  __shared__ int sb[256];
  sb[t] = v;
  __syncthreads();
  for (int d = 1; d < 128; d <<= 1) {
    int u = (lt >= d) ? sb[t - d] : 0;
    __syncthreads();
    sb[t] += u;
    __syncthreads();
  }
  if (lt < nb) ws[OFF_BPREF + (seg ? NB_N : 0) + lt] = sb[t] - v;
  if (t == 0) {
    ws[OFF_OFF_N + N_VAR] = NEDGE;
    ws[OFF_OFF_C + N_CSTR] = NEDGE;
  }
}

// ---------------------------------------------------------------------------
// Phase 3: per-block local exclusive scan + block prefix -> off[] and cur[].
// ---------------------------------------------------------------------------
__global__ __launch_bounds__(256) void scan_apply_k(int* __restrict__ ws) {
  int b = blockIdx.x;
  int seg = (b >= NB_N);
  const int* deg = ws + (seg ? OFF_DEG_C : OFF_DEG_N);
  int* off = ws + (seg ? OFF_OFF_C : OFF_OFF_N);
  int* cur = ws + (seg ? OFF_CUR_C : OFF_CUR_N);
  int n = seg ? N_CSTR : N_VAR;
  int lb = seg ? b - NB_N : b;
  int base = lb * 1024 + threadIdx.x * 4;
  int4 v = make_int4(0, 0, 0, 0);
  if (base + 4 <= n) {
    v = *reinterpret_cast<const int4*>(deg + base);
  } else {
    if (base < n) v.x = deg[base];
    if (base + 1 < n) v.y = deg[base + 1];
    if (base + 2 < n) v.z = deg[base + 2];
    if (base + 3 < n) v.w = deg[base + 3];
  }
  int s = v.x + v.y + v.z + v.w;
  __shared__ int sb[256];
  sb[threadIdx.x] = s;
  __syncthreads();
  for (int d = 1; d < 256; d <<= 1) {
    int u = (threadIdx.x >= d) ? sb[threadIdx.x - d] : 0;
    __syncthreads();
    sb[threadIdx.x] += u;
    __syncthreads();
  }
  int excl = sb[threadIdx.x] - s + ws[OFF_BPREF + b];
  int4 o;
  o.x = excl;
  o.y = o.x + v.x;
  o.z = o.y + v.y;
  o.w = o.z + v.z;
  if (base + 4 <= n) {
    *reinterpret_cast<int4*>(off + base) = o;
    *reinterpret_cast<int4*>(cur + base) = o;
  } else {
    if (base < n)     { off[base] = o.x;     cur[base] = o.x; }
    if (base + 1 < n) { off[base + 1] = o.y; cur[base + 1] = o.y; }
    if (base + 2 < n) { off[base + 2] = o.z; cur[base + 2] = o.z; }
    if (base + 3 < n) { off[base + 3] = o.w; cur[base + 3] = o.w; }
  }
}

// ---------------------------------------------------------------------------
// Fill CSR buckets: 4 edges per thread -> 8 independent returning atomics in
// flight (was 2), then 8 independent stores. Vector int4/float4 edge loads.
// ---------------------------------------------------------------------------
__global__ __launch_bounds__(256) void fill_k(const int4* __restrict__ es4,
                                              const int4* __restrict__ ed4,
                                              const float4* __restrict__ ea4,
                                              int* __restrict__ cur_node,
                                              int* __restrict__ cur_cstr,
                                              int2* __restrict__ ent_node,
                                              int2* __restrict__ ent_cstr) {
  int g = blockIdx.x * blockDim.x + threadIdx.x;
  if (g >= NEDGE / 4) return;
  int4 s = es4[g];
  int4 d = ed4[g];
  float4 w = ea4[g];
  int p0 = atomicAdd(&cur_node[d.x], 1);
  int p1 = atomicAdd(&cur_node[d.y], 1);
  int p2 = atomicAdd(&cur_node[d.z], 1);
  int p3 = atomicAdd(&cur_node[d.w], 1);
  int q0 = atomicAdd(&cur_cstr[s.x], 1);
  int q1 = atomicAdd(&cur_cstr[s.y], 1);
  int q2 = atomicAdd(&cur_cstr[s.z], 1);
  int q3 = atomicAdd(&cur_cstr[s.w], 1);
  ent_node[p0] = make_int2(s.x, __float_as_int(w.x));
  ent_node[p1] = make_int2(s.y, __float_as_int(w.y));
  ent_node[p2] = make_int2(s.z, __float_as_int(w.z));
  ent_node[p3] = make_int2(s.w, __float_as_int(w.w));
  ent_cstr[q0] = make_int2(d.x, __float_as_int(w.x));
  ent_cstr[q1] = make_int2(d.y, __float_as_int(w.y));
  ent_cstr[q2] = make_int2(d.z, __float_as_int(w.z));
  ent_cstr[q3] = make_int2(d.w, __float_as_int(w.w));
}

// ---------------------------------------------------------------------------
// Gather: one wave per destination row, lane = column. Unroll-8: entries
// loaded pairwise as 16B wave-uniform loads, 8 row-gathers in flight, dual
// accumulators. Prologue fixes entry alignment to 16B.
// ---------------------------------------------------------------------------
__global__ __launch_bounds__(256) void gather_k(
    const float* __restrict__ srcf, const int2* __restrict__ ent,
    const int* __restrict__ off, const float* __restrict__ ab_src,
    float* __restrict__ agg, int n) {
  int lane = threadIdx.x & 63;
  float a_s = ab_src[lane], b_s = ab_src[64 + lane];
  int r = __builtin_amdgcn_readfirstlane((blockIdx.x * blockDim.x + threadIdx.x) >> 6);
  if (r >= n) return;
  int beg = off[r], end = off[r + 1];
  float acc0 = 0.f, acc1 = 0.f;
  int e = beg;
  if (e < end && (e & 1)) {  // align to entry pair (16B)
    int2 p = ent[e];
    acc0 = fmaf(fmaf(srcf[p.x * DIM + lane], a_s, b_s), __int_as_float(p.y), acc0);
    ++e;
  }
  for (; e + 8 <= end; e += 8) {
    int4 p0 = *reinterpret_cast<const int4*>(&ent[e]);
    int4 p1 = *reinterpret_cast<const int4*>(&ent[e + 2]);
    int4 p2 = *reinterpret_cast<const int4*>(&ent[e + 4]);
    int4 p3 = *reinterpret_cast<const int4*>(&ent[e + 6]);
    float v0 = srcf[p0.x * DIM + lane];
    float v1 = srcf[p0.z * DIM + lane];
    float v2 = srcf[p1.x * DIM + lane];
    float v3 = srcf[p1.z * DIM + lane];
    float v4 = srcf[p2.x * DIM + lane];
    float v5 = srcf[p2.z * DIM + lane];
    float v6 = srcf[p3.x * DIM + lane];
    float v7 = srcf[p3.z * DIM + lane];
    acc0 = fmaf(fmaf(v0, a_s, b_s), __int_as_float(p0.y), acc0);
    acc1 = fmaf(fmaf(v1, a_s, b_s), __int_as_float(p0.w), acc1);
    acc0 = fmaf(fmaf(v2, a_s, b_s), __int_as_float(p1.y), acc0);
    acc1 = fmaf(fmaf(v3, a_s, b_s), __int_as_float(p1.w), acc1);
    acc0 = fmaf(fmaf(v4, a_s, b_s), __int_as_float(p2.y), acc0);
    acc1 = fmaf(fmaf(v5, a_s, b_s), __int_as_float(p2.w), acc1);
    acc0 = fmaf(fmaf(v6, a_s, b_s), __int_as_float(p3.y), acc0);
    acc1 = fmaf(fmaf(v7, a_s, b_s), __int_as_float(p3.w), acc1);
  }
  for (; e + 2 <= end; e += 2) {
    int4 p = *reinterpret_cast<const int4*>(&ent[e]);
    float v0 = srcf[p.x * DIM + lane];
    float v1 = srcf[p.z * DIM + lane];
    acc0 = fmaf(fmaf(v0, a_s, b_s), __int_as_float(p.y), acc0);
    acc1 = fmaf(fmaf(v1, a_s, b_s), __int_as_float(p.w), acc1);
  }
  if (e < end) {
    int2 p = ent[e];
    acc0 = fmaf(fmaf(srcf[p.x * DIM + lane], a_s, b_s), __int_as_float(p.y), acc0);
  }
  float acc = acc0 + acc1;
  agg[r * DIM + lane] = acc / fmaxf((float)(end - beg), 1.f);
}

// ---------------------------------------------------------------------------
// Output GEMM + epilogue in place; weights in registers, readlane broadcast.
// ---------------------------------------------------------------------------
__global__ __launch_bounds__(256) void out_k(
    const float* __restrict__ raw, const float* __restrict__ ab,
    const float* __restrict__ w_rel, const float* __restrict__ b_rel,
    const float* __restrict__ w_root, float* __restrict__ io, int n) {
  int lane = threadIdx.x & 63;
  float a = ab[lane], b = ab[64 + lane];
  float brel = b_rel[lane];
  float4 wr[16], wo[16];
#pragma unroll
  for (int i = 0; i < 16; ++i) {
    wr[i] = reinterpret_cast<const float4*>(w_rel + lane * DIM)[i];
    wo[i] = reinterpret_cast<const float4*>(w_root + lane * DIM)[i];
  }
  int wave = (blockIdx.x * blockDim.x + threadIdx.x) >> 6;
  int nw = (gridDim.x * blockDim.x) >> 6;
  for (int r = wave; r < n; r += nw) {
    float av = io[r * DIM + lane];
    float xv = fmaf(raw[r * DIM + lane], a, b);
    int avi = __float_as_int(av);
    int xvi = __float_as_int(xv);
    float acc0 = 0.f, acc1 = 0.f, acc2 = 0.f, acc3 = 0.f;
#pragma unroll
    for (int i = 0; i < 16; ++i) {
      acc0 = fmaf(__int_as_float(__builtin_amdgcn_readlane(avi, 4 * i + 0)), wr[i].x, acc0);
      acc1 = fmaf(__int_as_float(__builtin_amdgcn_readlane(avi, 4 * i + 1)), wr[i].y, acc1);
      acc2 = fmaf(__int_as_float(__builtin_amdgcn_readlane(avi, 4 * i + 2)), wr[i].z, acc2);
      acc3 = fmaf(__int_as_float(__builtin_amdgcn_readlane(avi, 4 * i + 3)), wr[i].w, acc3);
      acc0 = fmaf(__int_as_float(__builtin_amdgcn_readlane(xvi, 4 * i + 0)), wo[i].x, acc0);
      acc1 = fmaf(__int_as_float(__builtin_amdgcn_readlane(xvi, 4 * i + 1)), wo[i].y, acc1);
      acc2 = fmaf(__int_as_float(__builtin_amdgcn_readlane(xvi, 4 * i + 2)), wo[i].z, acc2);
      acc3 = fmaf(__int_as_float(__builtin_amdgcn_readlane(xvi, 4 * i + 3)), wo[i].w, acc3);
    }
    io[r * DIM + lane] = fmaxf((acc0 + acc1) + (acc2 + acc3) + brel + xv, 0.f);
  }
}

extern "C" void kernel_launch(void* const* d_in, const int* in_sizes, int n_in,
                              void* d_out, int out_size, void* d_ws, size_t ws_size,
                              hipStream_t stream) {
  const float* vf = (const float*)d_in[0];
  const float* cf = (const float*)d_in[1];
  const int* es = (const int*)d_in[2];
  const int* ed = (const int*)d_in[3];
  const float* ea = (const float*)d_in[4];
  const float* gn = (const float*)d_in[5];
  const float* bn = (const float*)d_in[6];
  const float* gc = (const float*)d_in[7];
  const float* bc = (const float*)d_in[8];
  const float* n_rel_w = (const float*)d_in[9];
  const float* n_rel_b = (const float*)d_in[10];
  const float* n_root_w = (const float*)d_in[11];
  const float* c_rel_w = (const float*)d_in[12];
  const float* c_rel_b = (const float*)d_in[13];
  const float* c_root_w = (const float*)d_in[14];
  float* out = (float*)d_out;
  int* wsi = (int*)d_ws;
  float* wsf = (float*)d_ws;

  float* stats = wsf + OFF_STATS;
  float* ab = wsf + OFF_AB;
  int* off_node = wsi + OFF_OFF_N;
  int* off_cstr = wsi + OFF_OFF_C;
  int* cur_node = wsi + OFF_CUR_N;
  int* cur_cstr = wsi + OFF_CUR_C;
  int* deg_node = wsi + OFF_DEG_N;
  int* deg_cstr = wsi + OFF_DEG_C;
  int2* ent_node = (int2*)(wsi + OFF_ENT_N);
  int2* ent_cstr = (int2*)(wsi + OFF_ENT_C);

  float* agg_node = out;            // d_out rows reused as agg scratch
  float* agg_cstr = out + 6400000;

  hipMemsetAsync(d_ws, 0, (size_t)WS_ZERO_N * sizeof(int), stream);

  bn_stats_k<<<512, 256, 0, stream>>>(vf, N_VAR, stats);
  bn_stats_k<<<512, 256, 0, stream>>>(cf, N_CSTR, stats + 128);
  bn_finalize_k<<<1, 128, 0, stream>>>(stats, gn, bn, gc, bc, ab);

  hist_k<<<(NEDGE / 4 + 255) / 256, 256, 0, stream>>>((const int4*)es, (const int4*)ed,
                                                      deg_node, deg_cstr);
  scan_part_k<<<NB_T, 256, 0, stream>>>(wsi);
  scan_meta_k<<<1, 256, 0, stream>>>(wsi);
  scan_apply_k<<<NB_T, 256, 0, stream>>>(wsi);
  fill_k<<<(NEDGE / 4 + 255) / 256, 256, 0, stream>>>((const int4*)es, (const int4*)ed,
                                                      (const float4*)ea, cur_node,
                                                      cur_cstr, ent_node, ent_cstr);

  gather_k<<<(N_VAR + 3) / 4, 256, 0, stream>>>(cf, ent_node, off_node, ab + 128,
                                                agg_node, N_VAR);
  gather_k<<<(N_CSTR + 3) / 4, 256, 0, stream>>>(vf, ent_cstr, off_cstr, ab,
                                                 agg_cstr, N_CSTR);

  out_k<<<1024, 256, 0, stream>>>(vf, ab, n_rel_w, n_rel_b, n_root_w, agg_node, N_VAR);
  out_k<<<512, 256, 0, stream>>>(cf, ab + 128, c_rel_w, c_rel_b, c_root_w, agg_cstr,
                                 N_CSTR);
}